// Round 6
// baseline (608.180 us; speedup 1.0000x reference)
//
#include <hip/hip_runtime.h>
#include <cstddef>

#define Bv 4
#define Nv 24
#define NTv 16
#define Tv 64
#define NP 25
#define NEGF (-1e30f)

// ---------------- workspace layout (floats) ----------------
#define BETAA_OFF 0         // [B][25][25][16 sym][24 head]            960000
#define BETAU_OFF 960000    // [B][25][25][64 sym]                     160000
#define RNT_OFF   1120000   // [B][2 d][24 h][16 A][16 sL][16 sR]      786432
#define T0_OFF    1906432   // [B][24 h][24 p][16 sL][16 A]            589824
#define T1_OFF    2496256   // [B][24 h][24 p][16 sR][16 A]            589824
#define T0L_OFF   3086080   // [B][24 h][16 sR][16 A]                  24576
#define T1R_OFF   3110656   // [B][24 h][16 sL][16 A]                  24576
#define D0_OFF    3135232   // [B][24 l][16 A]                         1536
#define D1_OFF    3136768   // [B][24 l][16 A]                         1536
#define EU_OFF    3138304   // [B][24 p][48 j]                         4608
#define MA_OFF    3142912   // [B][25][25][24 h] max_sym betaA         60000
#define MU_OFF    3202912   // [B][25][25]       max_sym betau(NT)     2500
#define WS_NEED   3205412

__device__ __forceinline__ float shflmax16(float v) {
  v = fmaxf(v, __shfl_xor(v, 8, 16));
  v = fmaxf(v, __shfl_xor(v, 4, 16));
  v = fmaxf(v, __shfl_xor(v, 2, 16));
  v = fmaxf(v, __shfl_xor(v, 1, 16));
  return v;
}

// ---- init: width-1 betau + exp(unary) table ----
__global__ void init_kernel(const float* __restrict__ unary, float* __restrict__ betau,
                            float* __restrict__ Eu) {
  int t = blockIdx.x * blockDim.x + threadIdx.x;
  if (t >= Bv * Nv * 48) return;
  int i = t % 48, kk = (t / 48) % Nv, b = t / (48 * Nv);
  float u = unary[(size_t)(b * Nv + kk) * Tv + 16 + i];
  betau[((size_t)(b * NP + kk) * NP + (kk + 1)) * Tv + 16 + i] = u;
  Eu[(size_t)(b * Nv + kk) * 48 + i] = __expf(u);
}

// ---- fused prep: block per (b,A,h); coalesced 32KB rule read; all precontractions ----
__global__ __launch_bounds__(256) void prep_kernel(
    const float* __restrict__ rule, const float* __restrict__ Eu,
    float* __restrict__ RNT, float* __restrict__ T0, float* __restrict__ T1,
    float* __restrict__ T0L, float* __restrict__ T1R,
    float* __restrict__ D0, float* __restrict__ D1) {
  const int h = blockIdx.x, A = blockIdx.y, b = blockIdx.z;
  const int t = threadIdx.x;  // 256
  __shared__ float er0[64 * 65];
  __shared__ float er1[64 * 65];
  __shared__ float E[24 * 48];
  __shared__ float red[256];

  for (int i = t; i < 24 * 48; i += 256) E[i] = Eu[(size_t)b * (24 * 48) + i];
  const float* rb = rule + (size_t)((b * NTv + A) * Nv + h) * 8192;
#pragma unroll
  for (int i = 0; i < 8; ++i) {
    int lin = i * 1024 + t * 4;  // sL*128 + sR*2 + d
    float4 v = *(const float4*)(rb + lin);
    int sL = lin >> 7, rem = (lin & 127) >> 1;
    er0[sL * 65 + rem] = __expf(v.x);
    er1[sL * 65 + rem] = __expf(v.y);
    er0[sL * 65 + rem + 1] = __expf(v.z);
    er1[sL * 65 + rem + 1] = __expf(v.w);
  }
  __syncthreads();
  {  // RNT, A-major
    float* dst0 = RNT + (((size_t)(b * 2 + 0) * Nv + h) * NTv + A) * 256;
    float* dst1 = RNT + (((size_t)(b * 2 + 1) * Nv + h) * NTv + A) * 256;
    dst0[t] = er0[(t >> 4) * 65 + (t & 15)];
    dst1[t] = er1[(t >> 4) * 65 + (t & 15)];
  }
  for (int o = t; o < 384; o += 256) {  // T0 / T1
    int p = o >> 4, sL = o & 15;
    const float* Ep = E + p * 48;
    const float* r0 = er0 + sL * 65 + 16;
    float a0 = 0.f, a1 = 0.f;
#pragma unroll 8
    for (int j = 0; j < 48; ++j) a0 += Ep[j] * r0[j];
#pragma unroll 8
    for (int i = 0; i < 48; ++i) a1 += Ep[i] * er1[(16 + i) * 65 + sL];
    T0[(((size_t)(b * Nv + h) * Nv + p) * NTv + sL) * NTv + A] = a0;
    T1[(((size_t)(b * Nv + h) * Nv + p) * NTv + sL) * NTv + A] = a1;
  }
  if (t < 16) {  // T0L
    float acc = 0.f;
    for (int i = 0; i < 48; ++i) acc += er0[(16 + i) * 65 + t];
    T0L[((size_t)(b * Nv + h) * NTv + t) * NTv + A] = acc;
  } else if (t < 32) {  // T1R
    int sL = t - 16;
    float acc = 0.f;
    for (int j = 0; j < 48; ++j) acc += er1[sL * 65 + 16 + j];
    T1R[((size_t)(b * Nv + h) * NTv + sL) * NTv + A] = acc;
  }
  // D0 / D1
  float acc0 = 0.f, acc1 = 0.f;
  const int hp = (h + 1 < 24) ? h + 1 : 0, hm = (h >= 1) ? h - 1 : 0;
  for (int e = t; e < 2304; e += 256) {
    int i = e / 48, j = e % 48;
    acc0 += E[hp * 48 + j] * er0[(16 + i) * 65 + 16 + j];
    acc1 += E[hm * 48 + i] * er1[(16 + i) * 65 + 16 + j];
  }
  red[t] = acc0;
  __syncthreads();
  if (t < 64) {
    float s = red[t] + red[t + 64] + red[t + 128] + red[t + 192];
#pragma unroll
    for (int off = 32; off; off >>= 1) s += __shfl_xor(s, off, 64);
    if (t == 0 && h <= 22) D0[((size_t)b * Nv + h) * NTv + A] = s;
  }
  __syncthreads();
  red[t] = acc1;
  __syncthreads();
  if (t < 64) {
    float s = red[t] + red[t + 64] + red[t + 128] + red[t + 192];
#pragma unroll
    for (int off = 32; off; off >>= 1) s += __shfl_xor(s, off, 64);
    if (t == 0 && h >= 1) D1[((size_t)b * Nv + (h - 1)) * NTv + A] = s;
  }
}

// edge-dot with preloaded T values (loads hoisted by caller)
__device__ __forceinline__ void edge_dot2(float v0, float v1, float v2, float v3,
                                          float t0, float t1, float t2, float t3,
                                          float& sh, float& S) {
  float mx = fmaxf(fmaxf(v0, v1), fmaxf(v2, v3));
  mx = fmaxf(mx, __shfl_xor(mx, 1, 64));
  mx = fmaxf(mx, __shfl_xor(mx, 2, 64));
  float dot = __expf(v0 - mx) * t0 + __expf(v1 - mx) * t1 +
              __expf(v2 - mx) * t2 + __expf(v3 - mx) * t3;
  dot += __shfl_xor(dot, 1, 64);
  dot += __shfl_xor(dot, 2, 64);
  sh = mx;
  S = dot;
}

// ---- width kernel: MLP-preloaded Phase A + hoisted-load Phase B + fused final ----
__global__ __launch_bounds__(768) void width_kernel5(
    const float* __restrict__ unary, float* __restrict__ betaA, float* __restrict__ betau,
    const float* __restrict__ RNT, const float* __restrict__ T0, const float* __restrict__ T1,
    const float* __restrict__ T0L, const float* __restrict__ T1R,
    const float* __restrict__ D0, const float* __restrict__ D1,
    float* __restrict__ MA, float* __restrict__ MU,
    const float* __restrict__ root, float* __restrict__ out, int W) {
  const int l = blockIdx.x, b = blockIdx.y;
  const int r = l + W;
  const int tid = threadIdx.x;

  __shared__ float U0[24 * 256], U1[24 * 256];
  __shared__ float sG0[24], sG1[24];
  __shared__ float cLs[16 * 25], ecRs[16 * 25];
  __shared__ float eLs[16], eeRs[16];
  __shared__ float pM[2 * 24 * 16], pS[2 * 24 * 16];
  __shared__ float sTmp[16 * 24];

  // ---- edge staging (no barrier needed until Phase B) ----
  if (W >= 3) {
    if (tid < 384) {
      int s = tid / 24, j = tid % 24, jj = j - l;
      float v = betaA[((size_t)(b * NP + l) * NP + (r - 1)) * 384 + s * 24 + j];
      if (jj >= 0 && jj < 24) cLs[s * 25 + jj] = v;
    } else {
      int t2 = tid - 384;
      int s = t2 / 24, j = t2 % 24, jj = j - l;
      float v = betaA[((size_t)(b * NP + (l + 1)) * NP + r) * 384 + s * 24 + j];
      if (jj >= 0 && jj < 24) ecRs[s * 25 + jj] = v;
    }
    if (tid < 16) eLs[tid] = betau[((size_t)(b * NP + l) * NP + (r - 1)) * Tv + tid];
    else if (tid >= 32 && tid < 48)
      eeRs[tid - 32] = betau[((size_t)(b * NP + (l + 1)) * NP + r) * Tv + (tid - 32)];
  }

  // ---- Phase A: fixed-shift, full-MLP preload ----
  const int g = tid >> 5, k = tid & 31;
  const int cnt = W - 3;  // interior splits m = l+2 .. r-2
  float U0r[8], U1r[8];
#pragma unroll
  for (int j = 0; j < 8; ++j) { U0r[j] = 0.f; U1r[j] = 0.f; }
  float G0 = NEGF, G1 = NEGF;

  if (g < W) {
    const int h = l + g;
    // pre-pass: lane i owns split m = l+2+i
    float pMAlm = NEGF, pMUlm = NEGF, pMAmr = NEGF, pMUmr = NEGF;
    float sh0 = NEGF, sh1 = NEGF;
    if (k < cnt) {
      int m = l + 2 + k;
      pMAlm = MA[((size_t)(b * NP + l) * NP + m) * 24 + h];
      pMUlm = MU[(size_t)(b * NP + l) * NP + m];
      pMAmr = MA[((size_t)(b * NP + m) * NP + r) * 24 + h];
      pMUmr = MU[(size_t)(b * NP + m) * NP + r];
      if (k >= g - 1) sh0 = pMAlm + pMUmr;
      if (k <= g - 2) sh1 = pMUlm + pMAmr;
    }
    float m0 = sh0, m1 = sh1;
#pragma unroll
    for (int off = 16; off; off >>= 1) {
      m0 = fmaxf(m0, __shfl_xor(m0, off, 32));
      m1 = fmaxf(m1, __shfl_xor(m1, off, 32));
    }
    G0 = m0;
    G1 = m1;
    float pw0 = (sh0 == NEGF) ? 0.f : __expf(sh0 - G0);
    float pw1 = (sh1 == NEGF) ? 0.f : __expf(sh1 - G1);

    if (cnt > 0) {
      size_t cbase, cstr, bbase, bstr;
      if (k < 16) {
        cbase = ((size_t)(b * NP + l) * NP) * 384 + (size_t)k * 24 + h;  // betaA[b,l,m]
        cstr = 384;
        bbase = ((size_t)(b * NP + l) * NP) * 64 + k;                    // betau[b,l,m]
        bstr = 64;
      } else {
        cbase = (size_t)(b * NP) * NP * 384 + (size_t)r * 384 + (size_t)(k - 16) * 24 + h;
        cstr = (size_t)NP * 384;
        bbase = (size_t)(b * NP) * NP * 64 + (size_t)r * 64 + (k - 16);
        bstr = (size_t)NP * 64;
      }
      // full preload: all split loads issued back-to-back (one vmcnt drain)
      float cvA[21], bvA[21];
#pragma unroll
      for (int i = 0; i < 21; ++i) {
        if (i < cnt) {
          cvA[i] = betaA[cbase + (size_t)(l + 2 + i) * cstr];
          bvA[i] = betau[bbase + (size_t)(l + 2 + i) * bstr];
        }
      }
#pragma unroll
      for (int i = 0; i < 21; ++i) {
        if (i < cnt) {
          float bMAlm = __shfl(pMAlm, i, 32), bMUlm = __shfl(pMUlm, i, 32);
          float bMAmr = __shfl(pMAmr, i, 32), bMUmr = __shfl(pMUmr, i, 32);
          float bw0 = __shfl(pw0, i, 32), bw1 = __shfl(pw1, i, 32);
          float subc = (k < 16) ? bMAlm : bMAmr;
          float subb = (k < 16) ? bMUlm : bMUmr;
          float eC = __expf(fminf(cvA[i] - subc, 0.f));
          float eB = __expf(fminf(bvA[i] - subb, 0.f));
          float s0 = __shfl(eB, 16 + (k & 15), 32) * bw0;
          float s1 = __shfl(eC, 16 + (k & 15), 32) * bw1;
#pragma unroll
          for (int j = 0; j < 8; ++j) {
            int sL = (k >> 4) + 2 * j;
            U0r[j] = fmaf(__shfl(eC, sL, 32), s0, U0r[j]);
            U1r[j] = fmaf(__shfl(eB, sL, 32), s1, U1r[j]);
          }
        }
      }
    }
#pragma unroll
    for (int j = 0; j < 8; ++j) {
      U0[g * 256 + k + 32 * j] = U0r[j];
      U1[g * 256 + k + 32 * j] = U1r[j];
    }
    if (k == 0) { sG0[g] = G0; sG1[g] = G1; }
  }
  __syncthreads();

  // ---- Phase B: per (head,dir) contraction; all global loads hoisted per round ----
  {
    const int w = tid >> 6, lane = tid & 63;
    const int A = lane >> 2, q = lane & 3;
    for (int p = w; p < 2 * W; p += 12) {
      const int hh = p >> 1, d = p & 1;
      const int h = l + hh;
      // hoist edge T loads (issue before RNT round so all overlap)
      bool hasE2 = false, hasE3 = false;
      const float* Tb2 = nullptr;
      const float* Tb3 = nullptr;
      if (W >= 3) {
        if (d == 0) {
          if (hh < W - 1) { hasE2 = true; Tb2 = T0 + (((size_t)(b * Nv + h) * Nv + (r - 1)) * NTv + 4 * q) * NTv + A; }
          if (hh == 0)    { hasE3 = true; Tb3 = T0L + ((size_t)(b * Nv + l) * NTv + 4 * q) * NTv + A; }
        } else {
          if (hh >= 1)    { hasE2 = true; Tb2 = T1 + (((size_t)(b * Nv + h) * Nv + l) * NTv + 4 * q) * NTv + A; }
          if (hh == W - 1){ hasE3 = true; Tb3 = T1R + ((size_t)(b * Nv + (r - 1)) * NTv + 4 * q) * NTv + A; }
        }
      }
      float t20 = 0.f, t21 = 0.f, t22 = 0.f, t23 = 0.f;
      float t30 = 0.f, t31 = 0.f, t32 = 0.f, t33 = 0.f;
      if (hasE2) { t20 = Tb2[0]; t21 = Tb2[16]; t22 = Tb2[32]; t23 = Tb2[48]; }
      if (hasE3) { t30 = Tb3[0]; t31 = Tb3[16]; t32 = Tb3[32]; t33 = Tb3[48]; }

      const float* Urow = (d ? U1 : U0) + hh * 256 + 4 * q;
      const float* Rb = RNT + (((size_t)(b * 2 + d) * Nv + h) * NTv + A) * 256 + 4 * q;
      float acc = 0.f;
#pragma unroll
      for (int sL = 0; sL < 16; ++sL) {
        float4 u = *(const float4*)(Urow + sL * 16);
        float4 rv = *(const float4*)(Rb + sL * 16);
        acc += u.x * rv.x + u.y * rv.y + u.z * rv.z + u.w * rv.w;
      }
      acc += __shfl_xor(acc, 1, 64);
      acc += __shfl_xor(acc, 2, 64);
      float Mi = d ? sG1[hh] : sG0[hh];
      float sh2 = NEGF, S2 = 0.f, sh3 = NEGF, S3 = 0.f;
      if (W >= 3) {
        if (hasE2) {
          if (d == 0)
            edge_dot2(cLs[(4 * q + 0) * 25 + hh], cLs[(4 * q + 1) * 25 + hh],
                      cLs[(4 * q + 2) * 25 + hh], cLs[(4 * q + 3) * 25 + hh],
                      t20, t21, t22, t23, sh2, S2);
          else
            edge_dot2(ecRs[(4 * q + 0) * 25 + hh], ecRs[(4 * q + 1) * 25 + hh],
                      ecRs[(4 * q + 2) * 25 + hh], ecRs[(4 * q + 3) * 25 + hh],
                      t20, t21, t22, t23, sh2, S2);
        }
        if (hasE3) {
          if (d == 0)
            edge_dot2(eeRs[4 * q + 0], eeRs[4 * q + 1], eeRs[4 * q + 2], eeRs[4 * q + 3],
                      t30, t31, t32, t33, sh3, S3);
          else
            edge_dot2(eLs[4 * q + 0], eLs[4 * q + 1], eLs[4 * q + 2], eLs[4 * q + 3],
                      t30, t31, t32, t33, sh3, S3);
        }
      } else {
        if (d == 0 && hh == 0) { sh2 = 0.f; S2 = D0[((size_t)b * Nv + l) * NTv + A]; }
        if (d == 1 && hh == 1) { sh2 = 0.f; S2 = D1[((size_t)b * Nv + l) * NTv + A]; }
      }
      float Mf = fmaxf(Mi, fmaxf(sh2, sh3));
      float Sf = acc * __expf(Mi - Mf) + S2 * __expf(sh2 - Mf) + S3 * __expf(sh3 - Mf);
      if (q == 0) {
        pM[(d * 24 + hh) * 16 + A] = Mf;
        pS[(d * 24 + hh) * 16 + A] = Sf;
      }
    }
  }
  __syncthreads();
  // combine dirs, write betaA + MA; prep betau input
  if (tid < 384) {
    int A2 = tid & 15, hh = tid >> 4;
    if (hh < W) {
      float M0 = pM[(0 * 24 + hh) * 16 + A2], S0 = pS[(0 * 24 + hh) * 16 + A2];
      float M1 = pM[(1 * 24 + hh) * 16 + A2], S1 = pS[(1 * 24 + hh) * 16 + A2];
      float nm = fmaxf(M0, M1);
      float s = S0 * __expf(M0 - nm) + S1 * __expf(M1 - nm);
      float val = nm + __logf(s);
      betaA[((size_t)(b * NP + l) * NP + r) * 384 + A2 * 24 + (l + hh)] = val;
      sTmp[A2 * 24 + hh] = val + unary[(size_t)(b * Nv + (l + hh)) * Tv + A2];
      float mv = shflmax16(val);
      if (A2 == 0) MA[((size_t)(b * NP + l) * NP + r) * 24 + (l + hh)] = mv;
    }
  }
  __syncthreads();
  if (tid < 16) {
    float mx = NEGF;
    for (int x = 0; x < W; ++x) mx = fmaxf(mx, sTmp[tid * 24 + x]);
    float s = 0.f;
    for (int x = 0; x < W; ++x) s += __expf(sTmp[tid * 24 + x] - mx);
    float v = mx + __logf(s);
    betau[((size_t)(b * NP + l) * NP + r) * Tv + tid] = v;
    float mv = shflmax16(v);
    if (tid == 0) MU[(size_t)(b * NP + l) * NP + r] = mv;
    // fused final for the root span (0,24): out[b] = lse_A(v + root)
    if (W == Nv && l == 0) {
      float qv = v + root[b * NTv + tid];
      float qmx = shflmax16(qv);
      float e = __expf(qv - qmx);
      e += __shfl_xor(e, 8, 16);
      e += __shfl_xor(e, 4, 16);
      e += __shfl_xor(e, 2, 16);
      e += __shfl_xor(e, 1, 16);
      if (tid == 0) out[b] = qmx + __logf(e);
    }
  }
}

// ================= fallback path (small ws): R1-style, known-correct =================
__global__ void init_betau_kernel(const float* __restrict__ unary, float* __restrict__ betau) {
  int t = blockIdx.x * blockDim.x + threadIdx.x;
  if (t >= Bv * Nv * 48) return;
  int i = t % 48, kk = (t / 48) % Nv, b = t / (48 * Nv);
  betau[((size_t)(b * NP + kk) * NP + (kk + 1)) * Tv + 16 + i] =
      unary[(size_t)(b * Nv + kk) * Tv + 16 + i];
}

__global__ __launch_bounds__(768) void width_kernel_fb(
    const float* __restrict__ unary, const float* __restrict__ rule,
    float* __restrict__ betaA, float* __restrict__ betau, int W) {
  const int l = blockIdx.x, b = blockIdx.y;
  const int r = l + W;
  const int tid = threadIdx.x;
  const int sub = tid & 1;
  const int pid = tid >> 1;
  const int A = pid & 15;
  const int hh = pid >> 4;
  const int h = l + hh;
  const bool act = (hh < W);
  const int sA = tid & 15, sH = tid >> 4;

  __shared__ float sER0[48], sEL1[48];
  __shared__ float sCL0[16 * 24], sCR1[16 * 24];
  __shared__ float sMaxL0[24], sMaxR1[24];
  __shared__ float sShR0, sShL1;
  __shared__ float sTmp[16 * 24];

  float runM = NEGF, runS = 0.f;
  for (int m = l + 1; m < r; ++m) {
    const int wl = m - l, wr = r - m;
    if (tid < 64) {
      const int n = (wr == 1) ? 48 : 16, s0 = (wr == 1) ? 16 : 0;
      float v = (tid < n) ? betau[(size_t)((b * NP + m) * NP + r) * Tv + s0 + tid] : NEGF;
      float mx = v;
#pragma unroll
      for (int off = 32; off; off >>= 1) mx = fmaxf(mx, __shfl_xor(mx, off, 64));
      if (tid == 0) sShR0 = mx;
      if (tid < n) sER0[tid] = v - mx;
    } else if (tid < 128) {
      const int j = tid - 64;
      const int n = (wl == 1) ? 48 : 16, s0 = (wl == 1) ? 16 : 0;
      float v = (j < n) ? betau[(size_t)((b * NP + l) * NP + m) * Tv + s0 + j] : NEGF;
      float mx = v;
#pragma unroll
      for (int off = 32; off; off >>= 1) mx = fmaxf(mx, __shfl_xor(mx, off, 64));
      if (j == 0) sShL1 = mx;
      if (j < n) sEL1[j] = v - mx;
    }
    if (tid < 384) {
      if (wl > 1 && sH < wl) {
        float v = betaA[(size_t)((b * NP + l) * NP + m) * 384 + sA * Nv + (l + sH)];
        float mx = v;
#pragma unroll
        for (int off = 8; off; off >>= 1) mx = fmaxf(mx, __shfl_xor(mx, off, 16));
        if (sA == 0) sMaxL0[sH] = mx;
        sCL0[sA * Nv + sH] = v - mx;
      }
      if (wr > 1 && sH >= wl && sH < W) {
        float v = betaA[(size_t)((b * NP + m) * NP + r) * 384 + sA * Nv + (l + sH)];
        float mx = v;
#pragma unroll
        for (int off = 8; off; off >>= 1) mx = fmaxf(mx, __shfl_xor(mx, off, 16));
        if (sA == 0) sMaxR1[sH] = mx;
        sCR1[sA * Nv + sH] = v - mx;
      }
    }
    __syncthreads();
    if (act) {
      if (hh < wl && (wl > 1 || hh == 0)) {
        const int nL = (wl == 1) ? 48 : 16, sL0 = (wl == 1) ? 16 : 0;
        const int nR = (wr == 1) ? 48 : 16, sR0 = (wr == 1) ? 16 : 0;
        const float shift = ((wl == 1) ? 0.f : sMaxL0[hh]) + sShR0;
        float part = 0.f;
        const float* rb = rule + (size_t)(((b * NTv + A) * Nv + h) * Tv) * Tv * 2;
        for (int i = sub; i < nL; i += 2) {
          const float cl = (wl == 1) ? 0.f : sCL0[i * Nv + hh];
          const float* rp = rb + (size_t)(sL0 + i) * Tv * 2 + sR0 * 2;
#pragma unroll 8
          for (int j = 0; j < nR; ++j) part += __expf(cl + sER0[j] + rp[j * 2]);
        }
        float nm = fmaxf(runM, shift);
        runS = runS * __expf(runM - nm) + part * __expf(shift - nm);
        runM = nm;
      }
      if (hh >= wl && (wr > 1 || hh == W - 1)) {
        const int nL = (wl == 1) ? 48 : 16, sL0 = (wl == 1) ? 16 : 0;
        const int nR = (wr == 1) ? 48 : 16, sR0 = (wr == 1) ? 16 : 0;
        const float shift = sShL1 + ((wr == 1) ? 0.f : sMaxR1[hh]);
        float part = 0.f;
        const float* rb = rule + (size_t)(((b * NTv + A) * Nv + h) * Tv) * Tv * 2 + 1;
        for (int i = sub; i < nL; i += 2) {
          const float el = sEL1[i];
          const float* rp = rb + (size_t)(sL0 + i) * Tv * 2 + sR0 * 2;
#pragma unroll 8
          for (int j = 0; j < nR; ++j) {
            const float cr = (wr == 1) ? 0.f : sCR1[j * Nv + hh];
            part += __expf(el + cr + rp[j * 2]);
          }
        }
        float nm = fmaxf(runM, shift);
        runS = runS * __expf(runM - nm) + part * __expf(shift - nm);
        runM = nm;
      }
    }
    __syncthreads();
  }
  if (act) {
    float om = __shfl_xor(runM, 1, 64);
    float os = __shfl_xor(runS, 1, 64);
    float nm = fmaxf(runM, om);
    float s = runS * __expf(runM - nm) + os * __expf(om - nm);
    if (sub == 0) {
      float val = nm + __logf(s);
      betaA[(size_t)((b * NP + l) * NP + r) * 384 + A * Nv + h] = val;
      sTmp[A * Nv + hh] = val + unary[(b * Nv + h) * Tv + A];
    }
  }
  __syncthreads();
  if (tid < 16) {
    float mx = NEGF;
    for (int x = 0; x < W; ++x) mx = fmaxf(mx, sTmp[tid * Nv + x]);
    float s = 0.f;
    for (int x = 0; x < W; ++x) s += __expf(sTmp[tid * Nv + x] - mx);
    betau[(size_t)((b * NP + l) * NP + r) * Tv + tid] = mx + __logf(s);
  }
}

__global__ void final_kernel(const float* __restrict__ betau, const float* __restrict__ root,
                             float* __restrict__ out) {
  int b = threadIdx.x;
  if (b < Bv) {
    float vals[NTv];
    float mx = NEGF;
#pragma unroll
    for (int A = 0; A < NTv; ++A) {
      float v = betau[(size_t)((b * NP + 0) * NP + Nv) * Tv + A] + root[b * NTv + A];
      vals[A] = v;
      mx = fmaxf(mx, v);
    }
    float s = 0.f;
#pragma unroll
    for (int A = 0; A < NTv; ++A) s += __expf(vals[A] - mx);
    out[b] = mx + __logf(s);
  }
}

extern "C" void kernel_launch(void* const* d_in, const int* in_sizes, int n_in,
                              void* d_out, int out_size, void* d_ws, size_t ws_size,
                              hipStream_t stream) {
  (void)in_sizes; (void)n_in; (void)out_size;
  const float* unary = (const float*)d_in[0];
  const float* rule  = (const float*)d_in[1];
  const float* root  = (const float*)d_in[2];
  float* out = (float*)d_out;
  float* ws = (float*)d_ws;
  float* betaA = ws + BETAA_OFF;
  float* betau = ws + BETAU_OFF;
  const bool fast = ws_size >= (size_t)WS_NEED * sizeof(float);

  if (fast) {
    float* RNT = ws + RNT_OFF;
    float* T0  = ws + T0_OFF;
    float* T1  = ws + T1_OFF;
    float* T0L = ws + T0L_OFF;
    float* T1R = ws + T1R_OFF;
    float* D0  = ws + D0_OFF;
    float* D1  = ws + D1_OFF;
    float* Eu  = ws + EU_OFF;
    float* MAp = ws + MA_OFF;
    float* MUp = ws + MU_OFF;
    init_kernel<<<(Bv * Nv * 48 + 255) / 256, 256, 0, stream>>>(unary, betau, Eu);
    prep_kernel<<<dim3(24, 16, 4), 256, 0, stream>>>(rule, Eu, RNT, T0, T1, T0L, T1R, D0, D1);
    for (int W = 2; W <= Nv; ++W) {
      dim3 grid(Nv - W + 1, Bv);
      width_kernel5<<<grid, 768, 0, stream>>>(unary, betaA, betau, RNT, T0, T1, T0L, T1R,
                                              D0, D1, MAp, MUp, root, out, W);
    }
  } else {
    init_betau_kernel<<<(Bv * Nv * 48 + 255) / 256, 256, 0, stream>>>(unary, betau);
    for (int W = 2; W <= Nv; ++W) {
      dim3 grid(Nv - W + 1, Bv);
      width_kernel_fb<<<grid, 768, 0, stream>>>(unary, rule, betaA, betau, W);
    }
    final_kernel<<<1, 64, 0, stream>>>(betau, root, out);
  }
}